// Round 1
// baseline (712.393 us; speedup 1.0000x reference)
//
#include <hip/hip_runtime.h>
#include <hip/hip_bf16.h>

// Dims fixed by the reference problem
#define D_DIM 512
#define H_DIM 512
#define O_DIM 768

using bf16x8 = __attribute__((ext_vector_type(8))) short;
using f32x4  = __attribute__((ext_vector_type(4))) float;

static __device__ __forceinline__ unsigned short f2bf(float f){
  unsigned u = __float_as_uint(f);
  u += 0x7fffu + ((u >> 16) & 1u);   // RNE
  return (unsigned short)(u >> 16);
}

static __device__ __forceinline__ float fast_tanh(float x){
  float e = __expf(2.f * x);         // inf-safe: x>>0 -> 1, x<<0 -> -1
  return 1.f - 2.f / (e + 1.f);
}

// ordered-uint encoding so atomicMax(unsigned) == float max
static __device__ __forceinline__ unsigned f2ord(float f){
  unsigned u = __float_as_uint(f);
  return (u & 0x80000000u) ? ~u : (u | 0x80000000u);
}
static __device__ __forceinline__ float ord2f(unsigned u){
  u = (u & 0x80000000u) ? (u & 0x7fffffffu) : ~u;
  return __uint_as_float(u);
}

// ---------------------------------------------------------------------------
// Tiled bf16 MFMA GEMM: C = A[M,512] * Bm[N,512]^T  (Bm row-major = B^T)
// MODE 0: scores[M] += sum_cols tanh(C + b1[col]) * w2[col]   (atomicAdd)
// MODE 1: out[M,outStride] = C + bias[col]
// Tile: 128x128, BK=64, 256 threads = 4 waves of 64x64 (4x4 frags of 16x16x32)
// ---------------------------------------------------------------------------
template<int MODE>
__launch_bounds__(256, 2)
__global__ void gemm_kernel(const float* __restrict__ A,
                            const float* __restrict__ Bm,
                            const float* __restrict__ bias,
                            const float* __restrict__ w2,
                            float* __restrict__ out,
                            int M, int outStride)
{
  __shared__ short lds_a[128*64];
  __shared__ short lds_b[128*64];

  const int tid  = threadIdx.x;
  const int lane = tid & 63;
  const int w    = tid >> 6;
  const int wr   = w >> 1, wc = w & 1;
  const int lr   = lane & 15;     // row-in-frag (A) / n-in-frag (B) / col (D)
  const int lk   = lane >> 4;     // k-group (A,B) / row-group (D)

  const int rowBase = blockIdx.x * 128;
  const int colBase = blockIdx.y * 128;

  f32x4 acc[4][4];
  #pragma unroll
  for (int i = 0; i < 4; ++i)
    #pragma unroll
    for (int j = 0; j < 4; ++j)
      acc[i][j] = (f32x4){0.f, 0.f, 0.f, 0.f};

  for (int kt = 0; kt < 512/64; ++kt){
    const int kOff = kt * 64;
    // stage A,B tiles fp32 -> bf16 into swizzled LDS (8 float4 each per thread)
    #pragma unroll
    for (int it = 0; it < 8; ++it){
      int i   = tid + it*256;
      int row = i >> 4, c4 = i & 15;
      int idx = (row*64 + c4*4) ^ ((row & 7) << 3);   // XOR swizzle (16B granule)

      float4 va = {0.f,0.f,0.f,0.f};
      int gRow = rowBase + row;
      if (gRow < M) va = *(const float4*)(A + (size_t)gRow*512 + kOff + c4*4);
      uint2 pa = { (unsigned)f2bf(va.x) | ((unsigned)f2bf(va.y) << 16),
                   (unsigned)f2bf(va.z) | ((unsigned)f2bf(va.w) << 16) };
      *(uint2*)&lds_a[idx] = pa;

      int gN = colBase + row;                          // N always multiple of 128
      float4 vb = *(const float4*)(Bm + (size_t)gN*512 + kOff + c4*4);
      uint2 pb = { (unsigned)f2bf(vb.x) | ((unsigned)f2bf(vb.y) << 16),
                   (unsigned)f2bf(vb.z) | ((unsigned)f2bf(vb.w) << 16) };
      *(uint2*)&lds_b[idx] = pb;
    }
    __syncthreads();
    #pragma unroll
    for (int kk = 0; kk < 2; ++kk){
      bf16x8 af[4], bfr[4];
      #pragma unroll
      for (int mf = 0; mf < 4; ++mf){
        int r   = wr*64 + mf*16 + lr;
        int idx = (r*64 + kk*32 + lk*8) ^ ((r & 7) << 3);
        af[mf] = *(bf16x8*)&lds_a[idx];
      }
      #pragma unroll
      for (int nf = 0; nf < 4; ++nf){
        int r   = wc*64 + nf*16 + lr;
        int idx = (r*64 + kk*32 + lk*8) ^ ((r & 7) << 3);
        bfr[nf] = *(bf16x8*)&lds_b[idx];
      }
      #pragma unroll
      for (int mf = 0; mf < 4; ++mf)
        #pragma unroll
        for (int nf = 0; nf < 4; ++nf)
          acc[mf][nf] = __builtin_amdgcn_mfma_f32_16x16x32_bf16(
              af[mf], bfr[nf], acc[mf][nf], 0, 0, 0);
    }
    __syncthreads();
  }

  if (MODE == 0){
    // scores epilogue: tanh + dot with w2, reduce over cols, atomicAdd partials
    #pragma unroll
    for (int mf = 0; mf < 4; ++mf){
      float part[4] = {0.f,0.f,0.f,0.f};
      #pragma unroll
      for (int nf = 0; nf < 4; ++nf){
        int gc = colBase + wc*64 + nf*16 + lr;
        float b = bias[gc], wv = w2[gc];
        #pragma unroll
        for (int r = 0; r < 4; ++r)
          part[r] += fast_tanh(acc[mf][nf][r] + b) * wv;
      }
      #pragma unroll
      for (int r = 0; r < 4; ++r){
        part[r] += __shfl_xor(part[r], 1);
        part[r] += __shfl_xor(part[r], 2);
        part[r] += __shfl_xor(part[r], 4);
        part[r] += __shfl_xor(part[r], 8);
      }
      if (lr == 0){
        int gr = rowBase + wr*64 + mf*16 + lk*4;
        #pragma unroll
        for (int r = 0; r < 4; ++r)
          if (gr + r < M) atomicAdd(&out[gr + r], part[r]);
      }
    }
  } else {
    #pragma unroll
    for (int mf = 0; mf < 4; ++mf){
      int gr = rowBase + wr*64 + mf*16 + lk*4;
      #pragma unroll
      for (int nf = 0; nf < 4; ++nf){
        int gc = colBase + wc*64 + nf*16 + lr;
        float b = bias[gc];
        #pragma unroll
        for (int r = 0; r < 4; ++r)
          if (gr + r < M) out[(size_t)(gr + r)*outStride + gc] = acc[mf][nf][r] + b;
      }
    }
  }
}

// ---------------------------------------------------------------------------
__global__ void edge_pass1(const int* __restrict__ edge, int E,
                           const float* __restrict__ scores,
                           unsigned* __restrict__ smax_o,
                           int* __restrict__ hist)
{
  int e = blockIdx.x*256 + threadIdx.x;
  if (e >= E) return;
  int p = edge[e], l = edge[E + e];
  atomicMax(&smax_o[p], f2ord(scores[l]));
  atomicAdd(&hist[p], 1);
}

__global__ void scan_kernel(const int* __restrict__ hist,
                            int* __restrict__ offsets, int P)
{
  __shared__ int s[1024];
  int t = threadIdx.x;
  int local[16]; int sum = 0;
  #pragma unroll
  for (int i = 0; i < 16; ++i){
    int idx = t*16 + i;
    local[i] = (idx < P) ? hist[idx] : 0;
    sum += local[i];
  }
  s[t] = sum;
  __syncthreads();
  for (int off = 1; off < 1024; off <<= 1){
    int v = (t >= off) ? s[t - off] : 0;
    __syncthreads();
    s[t] += v;
    __syncthreads();
  }
  int run = s[t] - sum;             // exclusive prefix
  #pragma unroll
  for (int i = 0; i < 16; ++i){
    int idx = t*16 + i;
    if (idx < P) offsets[idx] = run;
    run += local[i];
  }
}

__global__ void edge_pass2(const int* __restrict__ edge, int E,
                           const float* __restrict__ scores,
                           const unsigned* __restrict__ smax_o,
                           float* __restrict__ ex,
                           float* __restrict__ esum,
                           const int* __restrict__ offsets,
                           int* __restrict__ cursor,
                           int* __restrict__ sorted)
{
  int e = blockIdx.x*256 + threadIdx.x;
  if (e >= E) return;
  int p = edge[e], l = edge[E + e];
  float v = __expf(scores[l] - ord2f(smax_o[p]));
  ex[e] = v;
  atomicAdd(&esum[p], v);
  int pos = atomicAdd(&cursor[p], 1);
  sorted[offsets[p] + pos] = e;
}

// one block per patient: acc over its edges, 256 threads x float2 = 512 cols
__global__ void agg_kernel(const int* __restrict__ edge, int E,
                           const float* __restrict__ lesion_x,
                           const float* __restrict__ ex,
                           const float* __restrict__ esum,
                           const int* __restrict__ offsets,
                           const int* __restrict__ hist,
                           const int* __restrict__ sorted,
                           float* __restrict__ agg)
{
  int p = blockIdx.x;
  int n = hist[p];
  if (n == 0) return;               // agg row stays zero (memset)
  int start = offsets[p];
  float inv = 1.f / fmaxf(esum[p], 1e-12f);
  int t = threadIdx.x;
  float a0 = 0.f, a1 = 0.f;
  for (int i = 0; i < n; ++i){
    int e = sorted[start + i];
    int l = edge[E + e];
    float alpha = ex[e] * inv;
    float2 f = *(const float2*)(lesion_x + (size_t)l*512 + t*2);
    a0 += alpha * f.x;
    a1 += alpha * f.y;
  }
  agg[(size_t)p*512 + t*2]     = a0;
  agg[(size_t)p*512 + t*2 + 1] = a1;
}

// in-place LayerNorm over rows of 768 in d_out
__global__ void ln_kernel(float* __restrict__ out,
                          const float* __restrict__ gamma,
                          const float* __restrict__ beta)
{
  __shared__ float red1[4];
  __shared__ float red2[4];
  int p = blockIdx.x;
  float* row = out + (size_t)p*768;
  int t = threadIdx.x;
  float v0 = row[t], v1 = row[t+256], v2 = row[t+512];
  float s = v0 + v1 + v2;
  #pragma unroll
  for (int off = 32; off; off >>= 1) s += __shfl_down(s, off);
  int lane = t & 63, wv = t >> 6;
  if (lane == 0) red1[wv] = s;
  __syncthreads();
  float mean = (red1[0]+red1[1]+red1[2]+red1[3]) * (1.f/768.f);
  float d0 = v0-mean, d1 = v1-mean, d2 = v2-mean;
  float q = d0*d0 + d1*d1 + d2*d2;
  #pragma unroll
  for (int off = 32; off; off >>= 1) q += __shfl_down(q, off);
  if (lane == 0) red2[wv] = q;
  __syncthreads();
  float var = (red2[0]+red2[1]+red2[2]+red2[3]) * (1.f/768.f);
  float inv = rsqrtf(var + 1e-5f);
  row[t]     = d0*inv*gamma[t]     + beta[t];
  row[t+256] = d1*inv*gamma[t+256] + beta[t+256];
  row[t+512] = d2*inv*gamma[t+512] + beta[t+512];
}

// ---------------------------------------------------------------------------
extern "C" void kernel_launch(void* const* d_in, const int* in_sizes, int n_in,
                              void* d_out, int out_size, void* d_ws, size_t ws_size,
                              hipStream_t stream)
{
  const float* lesion_x = (const float*)d_in[0];
  const int*   edge     = (const int*)d_in[1];
  // d_in[2] = num_patients (device scalar) — P derived from out_size instead
  const float* W1    = (const float*)d_in[3];
  const float* b1    = (const float*)d_in[4];
  const float* W2    = (const float*)d_in[5];
  // d_in[6] = b2 — softmax-invariant uniform shift, mathematically cancels
  const float* Wp    = (const float*)d_in[7];
  const float* bp    = (const float*)d_in[8];
  const float* gamma = (const float*)d_in[9];
  const float* beta  = (const float*)d_in[10];

  const int L = in_sizes[0] / D_DIM;
  const int E = in_sizes[1] / 2;
  const int P = out_size / O_DIM;

  auto al = [](size_t x){ return (x + 255) & ~(size_t)255; };
  char* ws = (char*)d_ws;
  size_t oScores = 0;
  size_t oSmax   = oScores + al((size_t)L*4);
  size_t oEsum   = oSmax   + al((size_t)P*4);
  size_t oHist   = oEsum   + al((size_t)P*4);
  size_t oCursor = oHist   + al((size_t)P*4);
  size_t oAgg    = oCursor + al((size_t)P*4);
  size_t zeroEnd = oAgg    + (size_t)P*D_DIM*4;
  size_t oOff    = al(zeroEnd);
  size_t oEx     = oOff    + al((size_t)P*4);
  size_t oSorted = oEx     + al((size_t)E*4);

  float*    scores = (float*)(ws + oScores);
  unsigned* smax_o = (unsigned*)(ws + oSmax);
  float*    esum   = (float*)(ws + oEsum);
  int*      hist   = (int*)(ws + oHist);
  int*      cursor = (int*)(ws + oCursor);
  float*    agg    = (float*)(ws + oAgg);
  int*      offs   = (int*)(ws + oOff);
  float*    ex     = (float*)(ws + oEx);
  int*      sorted = (int*)(ws + oSorted);

  hipMemsetAsync(d_ws, 0, zeroEnd, stream);

  dim3 b256(256);
  // GEMM1: scores over all L lesions (b2 dropped — cancels in softmax)
  gemm_kernel<0><<<dim3((L + 127)/128, H_DIM/128), b256, 0, stream>>>(
      lesion_x, W1, b1, W2, scores, L, 0);

  int eb = (E + 255) / 256;
  edge_pass1<<<eb, b256, 0, stream>>>(edge, E, scores, smax_o, hist);
  scan_kernel<<<1, 1024, 0, stream>>>(hist, offs, P);
  edge_pass2<<<eb, b256, 0, stream>>>(edge, E, scores, smax_o, ex, esum,
                                      offs, cursor, sorted);
  agg_kernel<<<P, b256, 0, stream>>>(edge, E, lesion_x, ex, esum, offs, hist,
                                     sorted, agg);
  // GEMM2: proj -> d_out, bias fused
  gemm_kernel<1><<<dim3(P/128, O_DIM/128), b256, 0, stream>>>(
      agg, Wp, bp, nullptr, (float*)d_out, P, O_DIM);
  ln_kernel<<<P, b256, 0, stream>>>((float*)d_out, gamma, beta);
}

// Round 2
// 514.173 us; speedup vs baseline: 1.3855x; 1.3855x over previous
//
#include <hip/hip_runtime.h>
#include <hip/hip_bf16.h>

#define D_DIM 512
#define H_DIM 512
#define O_DIM 768

using bf16x8 = __attribute__((ext_vector_type(8))) short;
using f32x4  = __attribute__((ext_vector_type(4))) float;

static __device__ __forceinline__ unsigned short f2bf(float f){
  unsigned u = __float_as_uint(f);
  u += 0x7fffu + ((u >> 16) & 1u);   // RNE
  return (unsigned short)(u >> 16);
}

static __device__ __forceinline__ float fast_tanh(float x){
  float e = __expf(2.f * x);         // inf-safe: x>>0 -> 1, x<<0 -> -1
  return 1.f - 2.f / (e + 1.f);
}

// ordered-uint encoding so atomicMax(unsigned) == float max
static __device__ __forceinline__ unsigned f2ord(float f){
  unsigned u = __float_as_uint(f);
  return (u & 0x80000000u) ? ~u : (u | 0x80000000u);
}
static __device__ __forceinline__ float ord2f(unsigned u){
  u = (u & 0x80000000u) ? (u & 0x7fffffffu) : ~u;
  return __uint_as_float(u);
}

// async global->LDS, 16B per lane, wave-uniform LDS base + lane*16 dest
static __device__ __forceinline__ void gload16(const void* g, void* l){
  __builtin_amdgcn_global_load_lds(
      (const __attribute__((address_space(1))) void*)g,
      (__attribute__((address_space(3))) void*)l, 16, 0, 0);
}

// ---------------------------------------------------------------------------
// fp32 -> bf16 pack, 8 elems/thread/iter (16B stores)
// ---------------------------------------------------------------------------
__global__ void cvt_bf16(const float* __restrict__ in,
                         unsigned short* __restrict__ out, int n8)
{
  int stride = gridDim.x * blockDim.x;
  for (int i = blockIdx.x*blockDim.x + threadIdx.x; i < n8; i += stride){
    const float4* p = (const float4*)in + (size_t)i*2;
    float4 a = p[0], b = p[1];
    union { unsigned short us[8]; uint4 u4; } pk;
    pk.us[0]=f2bf(a.x); pk.us[1]=f2bf(a.y); pk.us[2]=f2bf(a.z); pk.us[3]=f2bf(a.w);
    pk.us[4]=f2bf(b.x); pk.us[5]=f2bf(b.y); pk.us[6]=f2bf(b.z); pk.us[7]=f2bf(b.w);
    ((uint4*)out)[i] = pk.u4;
  }
}

// ---------------------------------------------------------------------------
// bf16 MFMA GEMM, m97 structure: 128x128 tile, BK=64, global_load_lds staging
// with pre-swizzled global source granules; XOR-swizzled ds_read_b128.
// C = A[M,512] * Bm[N,512]^T
// MODE 0: scores[M] += sum_cols tanh(C + b1[col]) * w2[col]   (atomicAdd)
// MODE 1: out[M,outStride] = C + bias[col]
// grid: (N/128, ceil(M/128))  -- N fast so same-A blocks are L3-adjacent
// ---------------------------------------------------------------------------
template<int MODE>
__launch_bounds__(256, 2)
__global__ void gemm_bf16(const short* __restrict__ A,
                          const short* __restrict__ Bm,
                          const float* __restrict__ bias,
                          const float* __restrict__ w2,
                          float* __restrict__ out,
                          int M, int outStride)
{
  __shared__ short lds_a[128*64];
  __shared__ short lds_b[128*64];

  const int tid  = threadIdx.x;
  const int lane = tid & 63;
  const int w    = tid >> 6;
  const int wr   = w >> 1, wc = w & 1;
  const int lr   = lane & 15;
  const int lk   = lane >> 4;

  const int colBase = blockIdx.x * 128;
  const int rowBase = blockIdx.y * 128;

  f32x4 acc[4][4];
  #pragma unroll
  for (int i = 0; i < 4; ++i)
    #pragma unroll
    for (int j = 0; j < 4; ++j)
      acc[i][j] = (f32x4){0.f, 0.f, 0.f, 0.f};

  const int subrow = lane >> 3;                 // 0..7 within 8-row chunk
  const int gpre   = lane & 7;                  // granule slot in LDS

  for (int kt = 0; kt < 512/64; ++kt){
    const int kOff = kt * 64;
    // each wave stages 32 rows of A and 32 rows of B (4 calls x 8 rows each)
    #pragma unroll
    for (int c = 0; c < 4; ++c){
      int r    = w*32 + c*8 + subrow;           // tile row 0..127
      int gran = gpre ^ (r & 7);                // pre-swizzled source granule
      int gA   = rowBase + r; if (gA > M-1) gA = M-1;
      gload16(A  + (size_t)gA*512 + kOff + gran*8, &lds_a[(w*32 + c*8)*64]);
      int gB   = colBase + r;                   // N is multiple of 128
      gload16(Bm + (size_t)gB*512 + kOff + gran*8, &lds_b[(w*32 + c*8)*64]);
    }
    __syncthreads();                            // compiler drains vmcnt here
    #pragma unroll
    for (int kk = 0; kk < 2; ++kk){
      bf16x8 af[4], bfr[4];
      #pragma unroll
      for (int mf = 0; mf < 4; ++mf){
        int r   = wr*64 + mf*16 + lr;
        int idx = (r*64 + kk*32 + lk*8) ^ ((r & 7) << 3);
        af[mf] = *(bf16x8*)&lds_a[idx];
      }
      #pragma unroll
      for (int nf = 0; nf < 4; ++nf){
        int r   = wc*64 + nf*16 + lr;
        int idx = (r*64 + kk*32 + lk*8) ^ ((r & 7) << 3);
        bfr[nf] = *(bf16x8*)&lds_b[idx];
      }
      #pragma unroll
      for (int mf = 0; mf < 4; ++mf)
        #pragma unroll
        for (int nf = 0; nf < 4; ++nf)
          acc[mf][nf] = __builtin_amdgcn_mfma_f32_16x16x32_bf16(
              af[mf], bfr[nf], acc[mf][nf], 0, 0, 0);
    }
    __syncthreads();
  }

  if (MODE == 0){
    #pragma unroll
    for (int mf = 0; mf < 4; ++mf){
      float part[4] = {0.f,0.f,0.f,0.f};
      #pragma unroll
      for (int nf = 0; nf < 4; ++nf){
        int gc = colBase + wc*64 + nf*16 + lr;
        float b = bias[gc], wv = w2[gc];
        #pragma unroll
        for (int r = 0; r < 4; ++r)
          part[r] += fast_tanh(acc[mf][nf][r] + b) * wv;
      }
      #pragma unroll
      for (int r = 0; r < 4; ++r){
        part[r] += __shfl_xor(part[r], 1);
        part[r] += __shfl_xor(part[r], 2);
        part[r] += __shfl_xor(part[r], 4);
        part[r] += __shfl_xor(part[r], 8);
      }
      if (lr == 0){
        int gr = rowBase + wr*64 + mf*16 + lk*4;
        #pragma unroll
        for (int r = 0; r < 4; ++r)
          if (gr + r < M) atomicAdd(&out[gr + r], part[r]);
      }
    }
  } else {
    #pragma unroll
    for (int mf = 0; mf < 4; ++mf){
      int gr = rowBase + wr*64 + mf*16 + lk*4;
      #pragma unroll
      for (int nf = 0; nf < 4; ++nf){
        int gc = colBase + wc*64 + nf*16 + lr;
        float b = bias[gc];
        #pragma unroll
        for (int r = 0; r < 4; ++r)
          if (gr + r < M) out[(size_t)(gr + r)*outStride + gc] = acc[mf][nf][r] + b;
      }
    }
  }
}

// ---------------------------------------------------------------------------
// Fallback fp32-input GEMM (reg-staged conversion) -- used if ws too small
// ---------------------------------------------------------------------------
template<int MODE>
__launch_bounds__(256, 2)
__global__ void gemm_conv(const float* __restrict__ A,
                          const float* __restrict__ Bm,
                          const float* __restrict__ bias,
                          const float* __restrict__ w2,
                          float* __restrict__ out,
                          int M, int outStride)
{
  __shared__ short lds_a[128*64];
  __shared__ short lds_b[128*64];

  const int tid  = threadIdx.x;
  const int lane = tid & 63;
  const int w    = tid >> 6;
  const int wr   = w >> 1, wc = w & 1;
  const int lr   = lane & 15;
  const int lk   = lane >> 4;
  const int rowBase = blockIdx.y * 128;
  const int colBase = blockIdx.x * 128;

  f32x4 acc[4][4];
  #pragma unroll
  for (int i = 0; i < 4; ++i)
    #pragma unroll
    for (int j = 0; j < 4; ++j)
      acc[i][j] = (f32x4){0.f, 0.f, 0.f, 0.f};

  for (int kt = 0; kt < 512/64; ++kt){
    const int kOff = kt * 64;
    #pragma unroll
    for (int it = 0; it < 8; ++it){
      int i   = tid + it*256;
      int row = i >> 4, c4 = i & 15;
      int idx = (row*64 + c4*4) ^ ((row & 7) << 3);
      float4 va = {0.f,0.f,0.f,0.f};
      int gRow = rowBase + row;
      if (gRow < M) va = *(const float4*)(A + (size_t)gRow*512 + kOff + c4*4);
      uint2 pa = { (unsigned)f2bf(va.x) | ((unsigned)f2bf(va.y) << 16),
                   (unsigned)f2bf(va.z) | ((unsigned)f2bf(va.w) << 16) };
      *(uint2*)&lds_a[idx] = pa;
      int gN = colBase + row;
      float4 vb = *(const float4*)(Bm + (size_t)gN*512 + kOff + c4*4);
      uint2 pb = { (unsigned)f2bf(vb.x) | ((unsigned)f2bf(vb.y) << 16),
                   (unsigned)f2bf(vb.z) | ((unsigned)f2bf(vb.w) << 16) };
      *(uint2*)&lds_b[idx] = pb;
    }
    __syncthreads();
    #pragma unroll
    for (int kk = 0; kk < 2; ++kk){
      bf16x8 af[4], bfr[4];
      #pragma unroll
      for (int mf = 0; mf < 4; ++mf){
        int r   = wr*64 + mf*16 + lr;
        int idx = (r*64 + kk*32 + lk*8) ^ ((r & 7) << 3);
        af[mf] = *(bf16x8*)&lds_a[idx];
      }
      #pragma unroll
      for (int nf = 0; nf < 4; ++nf){
        int r   = wc*64 + nf*16 + lr;
        int idx = (r*64 + kk*32 + lk*8) ^ ((r & 7) << 3);
        bfr[nf] = *(bf16x8*)&lds_b[idx];
      }
      #pragma unroll
      for (int mf = 0; mf < 4; ++mf)
        #pragma unroll
        for (int nf = 0; nf < 4; ++nf)
          acc[mf][nf] = __builtin_amdgcn_mfma_f32_16x16x32_bf16(
              af[mf], bfr[nf], acc[mf][nf], 0, 0, 0);
    }
    __syncthreads();
  }

  if (MODE == 0){
    #pragma unroll
    for (int mf = 0; mf < 4; ++mf){
      float part[4] = {0.f,0.f,0.f,0.f};
      #pragma unroll
      for (int nf = 0; nf < 4; ++nf){
        int gc = colBase + wc*64 + nf*16 + lr;
        float b = bias[gc], wv = w2[gc];
        #pragma unroll
        for (int r = 0; r < 4; ++r)
          part[r] += fast_tanh(acc[mf][nf][r] + b) * wv;
      }
      #pragma unroll
      for (int r = 0; r < 4; ++r){
        part[r] += __shfl_xor(part[r], 1);
        part[r] += __shfl_xor(part[r], 2);
        part[r] += __shfl_xor(part[r], 4);
        part[r] += __shfl_xor(part[r], 8);
      }
      if (lr == 0){
        int gr = rowBase + wr*64 + mf*16 + lk*4;
        #pragma unroll
        for (int r = 0; r < 4; ++r)
          if (gr + r < M) atomicAdd(&out[gr + r], part[r]);
      }
    }
  } else {
    #pragma unroll
    for (int mf = 0; mf < 4; ++mf){
      int gr = rowBase + wr*64 + mf*16 + lk*4;
      #pragma unroll
      for (int nf = 0; nf < 4; ++nf){
        int gc = colBase + wc*64 + nf*16 + lr;
        float b = bias[gc];
        #pragma unroll
        for (int r = 0; r < 4; ++r)
          if (gr + r < M) out[(size_t)(gr + r)*outStride + gc] = acc[mf][nf][r] + b;
      }
    }
  }
}

// ---------------------------------------------------------------------------
__global__ void edge_pass1(const int* __restrict__ edge, int E,
                           const float* __restrict__ scores,
                           unsigned* __restrict__ smax_o,
                           int* __restrict__ hist)
{
  int e = blockIdx.x*256 + threadIdx.x;
  if (e >= E) return;
  int p = edge[e], l = edge[E + e];
  atomicMax(&smax_o[p], f2ord(scores[l]));
  atomicAdd(&hist[p], 1);
}

__global__ void scan_kernel(const int* __restrict__ hist,
                            int* __restrict__ offsets, int P)
{
  __shared__ int s[1024];
  int t = threadIdx.x;
  int local[16]; int sum = 0;
  #pragma unroll
  for (int i = 0; i < 16; ++i){
    int idx = t*16 + i;
    local[i] = (idx < P) ? hist[idx] : 0;
    sum += local[i];
  }
  s[t] = sum;
  __syncthreads();
  for (int off = 1; off < 1024; off <<= 1){
    int v = (t >= off) ? s[t - off] : 0;
    __syncthreads();
    s[t] += v;
    __syncthreads();
  }
  int run = s[t] - sum;             // exclusive prefix
  #pragma unroll
  for (int i = 0; i < 16; ++i){
    int idx = t*16 + i;
    if (idx < P) offsets[idx] = run;
    run += local[i];
  }
}

__global__ void edge_pass2(const int* __restrict__ edge, int E,
                           const float* __restrict__ scores,
                           const unsigned* __restrict__ smax_o,
                           float* __restrict__ ex,
                           float* __restrict__ esum,
                           const int* __restrict__ offsets,
                           int* __restrict__ cursor,
                           int* __restrict__ sorted)
{
  int e = blockIdx.x*256 + threadIdx.x;
  if (e >= E) return;
  int p = edge[e], l = edge[E + e];
  float v = __expf(scores[l] - ord2f(smax_o[p]));
  ex[e] = v;
  atomicAdd(&esum[p], v);
  int pos = atomicAdd(&cursor[p], 1);
  sorted[offsets[p] + pos] = e;
}

// one block per patient: 256 threads x 2 cols. BF=true writes packed bf16.
template<bool BF>
__global__ void agg_kernel(const int* __restrict__ edge, int E,
                           const float* __restrict__ lesion_x,
                           const float* __restrict__ ex,
                           const float* __restrict__ esum,
                           const int* __restrict__ offsets,
                           const int* __restrict__ hist,
                           const int* __restrict__ sorted,
                           float* __restrict__ aggf,
                           unsigned* __restrict__ aggb)
{
  int p = blockIdx.x;
  int n = hist[p];
  if (n == 0) return;               // row stays zero (memset)
  int start = offsets[p];
  float inv = 1.f / fmaxf(esum[p], 1e-12f);
  int t = threadIdx.x;
  float a0 = 0.f, a1 = 0.f;
  for (int i = 0; i < n; ++i){
    int e = sorted[start + i];
    int l = edge[E + e];
    float alpha = ex[e] * inv;
    float2 f = *(const float2*)(lesion_x + (size_t)l*512 + t*2);
    a0 += alpha * f.x;
    a1 += alpha * f.y;
  }
  if (BF){
    aggb[(size_t)p*256 + t] = (unsigned)f2bf(a0) | ((unsigned)f2bf(a1) << 16);
  } else {
    aggf[(size_t)p*512 + t*2]     = a0;
    aggf[(size_t)p*512 + t*2 + 1] = a1;
  }
}

// in-place LayerNorm over rows of 768 in d_out
__global__ void ln_kernel(float* __restrict__ out,
                          const float* __restrict__ gamma,
                          const float* __restrict__ beta)
{
  __shared__ float red1[4];
  __shared__ float red2[4];
  int p = blockIdx.x;
  float* row = out + (size_t)p*768;
  int t = threadIdx.x;
  float v0 = row[t], v1 = row[t+256], v2 = row[t+512];
  float s = v0 + v1 + v2;
  #pragma unroll
  for (int off = 32; off; off >>= 1) s += __shfl_down(s, off);
  int lane = t & 63, wv = t >> 6;
  if (lane == 0) red1[wv] = s;
  __syncthreads();
  float mean = (red1[0]+red1[1]+red1[2]+red1[3]) * (1.f/768.f);
  float d0 = v0-mean, d1 = v1-mean, d2 = v2-mean;
  float q = d0*d0 + d1*d1 + d2*d2;
  #pragma unroll
  for (int off = 32; off; off >>= 1) q += __shfl_down(q, off);
  if (lane == 0) red2[wv] = q;
  __syncthreads();
  float var = (red2[0]+red2[1]+red2[2]+red2[3]) * (1.f/768.f);
  float inv = rsqrtf(var + 1e-5f);
  row[t]     = d0*inv*gamma[t]     + beta[t];
  row[t+256] = d1*inv*gamma[t+256] + beta[t+256];
  row[t+512] = d2*inv*gamma[t+512] + beta[t+512];
}

// ---------------------------------------------------------------------------
extern "C" void kernel_launch(void* const* d_in, const int* in_sizes, int n_in,
                              void* d_out, int out_size, void* d_ws, size_t ws_size,
                              hipStream_t stream)
{
  const float* lesion_x = (const float*)d_in[0];
  const int*   edge     = (const int*)d_in[1];
  const float* W1    = (const float*)d_in[3];
  const float* b1    = (const float*)d_in[4];
  const float* W2    = (const float*)d_in[5];
  // d_in[6] = b2 — uniform shift, cancels in softmax
  const float* Wp    = (const float*)d_in[7];
  const float* bp    = (const float*)d_in[8];
  const float* gamma = (const float*)d_in[9];
  const float* beta  = (const float*)d_in[10];

  const int L = in_sizes[0] / D_DIM;
  const int E = in_sizes[1] / 2;
  const int P = out_size / O_DIM;

  auto al = [](size_t x){ return (x + 255) & ~(size_t)255; };
  char* ws = (char*)d_ws;
  size_t oScores = 0;
  size_t oSmax   = oScores + al((size_t)L*4);
  size_t oEsum   = oSmax   + al((size_t)P*4);
  size_t oHist   = oEsum   + al((size_t)P*4);
  size_t oCursor = oHist   + al((size_t)P*4);
  size_t smallEnd= oCursor + al((size_t)P*4);
  size_t oAggB   = smallEnd;                       // P*512*2 bf16
  size_t oAggF   = oAggB   + al((size_t)P*D_DIM*2);// P*512*4 fp32 (fallback)
  size_t oOff    = oAggF   + al((size_t)P*D_DIM*4);
  size_t oEx     = oOff    + al((size_t)P*4);
  size_t oSorted = oEx     + al((size_t)E*4);
  size_t oAb     = oSorted + al((size_t)E*4);      // L*512 bf16
  size_t oW1b    = oAb     + al((size_t)L*D_DIM*2);
  size_t oWpb    = oW1b    + al((size_t)H_DIM*D_DIM*2);
  size_t need    = oWpb    + al((size_t)O_DIM*D_DIM*2);

  float*    scores = (float*)(ws + oScores);
  unsigned* smax_o = (unsigned*)(ws + oSmax);
  float*    esum   = (float*)(ws + oEsum);
  int*      hist   = (int*)(ws + oHist);
  int*      cursor = (int*)(ws + oCursor);
  unsigned* aggb   = (unsigned*)(ws + oAggB);
  float*    aggf   = (float*)(ws + oAggF);
  int*      offs   = (int*)(ws + oOff);
  float*    ex     = (float*)(ws + oEx);
  int*      sorted = (int*)(ws + oSorted);
  short*    Ab     = (short*)(ws + oAb);
  short*    W1b    = (short*)(ws + oW1b);
  short*    Wpb    = (short*)(ws + oWpb);

  const bool big = (ws_size >= need);

  hipMemsetAsync(d_ws, 0, smallEnd, stream);
  dim3 b256(256);
  int eb = (E + 255) / 256;

  if (big){
    hipMemsetAsync(ws + oAggB, 0, (size_t)P*D_DIM*2, stream);
    // pre-convert to bf16 (BW-bound)
    cvt_bf16<<<2048, b256, 0, stream>>>(lesion_x, (unsigned short*)Ab, L*D_DIM/8);
    cvt_bf16<<<128,  b256, 0, stream>>>(W1, (unsigned short*)W1b, H_DIM*D_DIM/8);
    cvt_bf16<<<192,  b256, 0, stream>>>(Wp, (unsigned short*)Wpb, O_DIM*D_DIM/8);
    // GEMM1: scores (N fast in grid.x for A-tile L3 reuse)
    gemm_bf16<0><<<dim3(H_DIM/128, (L + 127)/128), b256, 0, stream>>>(
        Ab, W1b, b1, W2, scores, L, 0);
    edge_pass1<<<eb, b256, 0, stream>>>(edge, E, scores, smax_o, hist);
    scan_kernel<<<1, 1024, 0, stream>>>(hist, offs, P);
    edge_pass2<<<eb, b256, 0, stream>>>(edge, E, scores, smax_o, ex, esum,
                                        offs, cursor, sorted);
    agg_kernel<true><<<P, b256, 0, stream>>>(edge, E, lesion_x, ex, esum, offs,
                                             hist, sorted, nullptr, aggb);
    gemm_bf16<1><<<dim3(O_DIM/128, P/128), b256, 0, stream>>>(
        (const short*)aggb, Wpb, bp, nullptr, (float*)d_out, P, O_DIM);
  } else {
    hipMemsetAsync(ws + oAggF, 0, (size_t)P*D_DIM*4, stream);
    gemm_conv<0><<<dim3(H_DIM/128, (L + 127)/128), b256, 0, stream>>>(
        lesion_x, W1, b1, W2, scores, L, 0);
    edge_pass1<<<eb, b256, 0, stream>>>(edge, E, scores, smax_o, hist);
    scan_kernel<<<1, 1024, 0, stream>>>(hist, offs, P);
    edge_pass2<<<eb, b256, 0, stream>>>(edge, E, scores, smax_o, ex, esum,
                                        offs, cursor, sorted);
    agg_kernel<false><<<P, b256, 0, stream>>>(edge, E, lesion_x, ex, esum, offs,
                                              hist, sorted, aggf, nullptr);
    gemm_conv<1><<<dim3(O_DIM/128, P/128), b256, 0, stream>>>(
        aggf, Wp, bp, nullptr, (float*)d_out, P, O_DIM);
  }
  ln_kernel<<<P, b256, 0, stream>>>((float*)d_out, gamma, beta);
}

// Round 3
// 430.024 us; speedup vs baseline: 1.6566x; 1.1957x over previous
//
#include <hip/hip_runtime.h>
#include <hip/hip_bf16.h>

#define D_DIM 512
#define H_DIM 512
#define O_DIM 768

using bf16x8 = __attribute__((ext_vector_type(8))) short;
using f32x4  = __attribute__((ext_vector_type(4))) float;

static __device__ __forceinline__ unsigned short f2bf(float f){
  unsigned u = __float_as_uint(f);
  u += 0x7fffu + ((u >> 16) & 1u);   // RNE
  return (unsigned short)(u >> 16);
}

// packed fp32x2 -> bf16x2 (RNE), one VALU inst
static __device__ __forceinline__ unsigned cvtpk(float lo, float hi){
  unsigned r;
  asm("v_cvt_pk_bf16_f32 %0, %1, %2" : "=v"(r) : "v"(lo), "v"(hi));
  return r;
}

static __device__ __forceinline__ float fast_tanh(float x){
  float e = __expf(2.f * x);         // inf-safe: x>>0 -> 1, x<<0 -> -1
  return 1.f - 2.f / (e + 1.f);
}

// ordered-uint encoding so atomicMax(unsigned) == float max
static __device__ __forceinline__ unsigned f2ord(float f){
  unsigned u = __float_as_uint(f);
  return (u & 0x80000000u) ? ~u : (u | 0x80000000u);
}
static __device__ __forceinline__ float ord2f(unsigned u){
  u = (u & 0x80000000u) ? (u & 0x7fffffffu) : ~u;
  return __uint_as_float(u);
}

// async global->LDS, 16B per lane, wave-uniform LDS base + lane*16 dest
static __device__ __forceinline__ void gload16(const void* g, void* l){
  __builtin_amdgcn_global_load_lds(
      (const __attribute__((address_space(1))) void*)g,
      (__attribute__((address_space(3))) void*)l, 16, 0, 0);
}

// ---------------------------------------------------------------------------
// fp32 -> bf16 pack, 8 elems/thread/iter (16B stores) -- only for W1/Wp now
// ---------------------------------------------------------------------------
__global__ void cvt_bf16(const float* __restrict__ in,
                         unsigned short* __restrict__ out, int n8)
{
  int stride = gridDim.x * blockDim.x;
  for (int i = blockIdx.x*blockDim.x + threadIdx.x; i < n8; i += stride){
    const float4* p = (const float4*)in + (size_t)i*2;
    float4 a = p[0], b = p[1];
    union { unsigned short us[8]; uint4 u4; } pk;
    pk.us[0]=f2bf(a.x); pk.us[1]=f2bf(a.y); pk.us[2]=f2bf(a.z); pk.us[3]=f2bf(a.w);
    pk.us[4]=f2bf(b.x); pk.us[5]=f2bf(b.y); pk.us[6]=f2bf(b.z); pk.us[7]=f2bf(b.w);
    ((uint4*)out)[i] = pk.u4;
  }
}

// ---------------------------------------------------------------------------
// GEMM1: scores = sum_cols tanh(A_fp32 @ W1b^T + b1) * w2   (atomicAdd partials)
// A staged fp32 via global_load_lds (16B-granule XOR pre-swizzle on source),
// converted to bf16 in regs with v_cvt_pk_bf16_f32. B staged bf16.
// 128x128 tile, BK=64, 4 waves = 2x2 of 64x64. Flat grid + bijective XCD
// chunked swizzle (N-fast) so the 4 col-blocks of one A row-panel share an L2.
// ---------------------------------------------------------------------------
__launch_bounds__(256, 2)
__global__ void gemm1_f32a(const float* __restrict__ A,
                           const short* __restrict__ Bm,
                           const float* __restrict__ bias,
                           const float* __restrict__ w2,
                           float* __restrict__ out,
                           int M, int nwg)
{
  __shared__ float lds_af[128*64];   // 32 KB
  __shared__ short lds_b [128*64];   // 16 KB

  // bijective XCD-chunked swizzle (m204), then N-fast decode
  {
  }
  const int q  = nwg >> 3, rr = nwg & 7;
  const int xcd = blockIdx.x & 7, bidx = blockIdx.x >> 3;
  const int swz = (xcd < rr ? xcd*(q+1) : rr*(q+1) + (xcd-rr)*q) + bidx;
  const int colBase = (swz & 3) * 128;
  const int rowBase = (swz >> 2) * 128;

  const int tid  = threadIdx.x;
  const int lane = tid & 63;
  const int w    = tid >> 6;
  const int wr   = w >> 1, wc = w & 1;
  const int lr   = lane & 15;
  const int lk   = lane >> 4;

  f32x4 acc[4][4];
  #pragma unroll
  for (int i = 0; i < 4; ++i)
    #pragma unroll
    for (int j = 0; j < 4; ++j)
      acc[i][j] = (f32x4){0.f, 0.f, 0.f, 0.f};

  const int rlocA = lane >> 4;      // 0..3   (4 rows / A-call)
  const int jA    = lane & 15;      // 16B granule in 256B row
  const int rlocB = lane >> 3;      // 0..7   (8 rows / B-call)
  const int jB    = lane & 7;       // 16B granule in 128B row

  for (int kt = 0; kt < 512/64; ++kt){
    const int kOff = kt * 64;
    // stage A: 8 calls x 4 rows, fp32, source pre-swizzled at 16B granule
    #pragma unroll
    for (int c = 0; c < 8; ++c){
      int rt = w*32 + c*4 + rlocA;
      int gA = rowBase + rt; if (gA > M-1) gA = M-1;
      int js = jA ^ (rt & 7);
      gload16(A + (size_t)gA*512 + kOff + js*4, &lds_af[(w*32 + c*4)*64]);
    }
    // stage B: 4 calls x 8 rows, bf16
    #pragma unroll
    for (int c = 0; c < 4; ++c){
      int rt = w*32 + c*8 + rlocB;
      int gB = colBase + rt;
      int js = jB ^ (rt & 7);
      gload16(Bm + (size_t)gB*512 + kOff + js*8, &lds_b[(w*32 + c*8)*64]);
    }
    __syncthreads();
    #pragma unroll
    for (int kk = 0; kk < 2; ++kk){
      bf16x8 af[4], bfr[4];
      #pragma unroll
      for (int mf = 0; mf < 4; ++mf){
        int r   = wr*64 + mf*16 + lr;
        int rx  = r & 7;
        int g0  = kk*8 + lk*2;
        float4 lo4 = *(const float4*)&lds_af[r*64 + ((g0     ^ rx) << 2)];
        float4 hi4 = *(const float4*)&lds_af[r*64 + (((g0+1) ^ rx) << 2)];
        union { bf16x8 v; unsigned u[4]; } fa;
        fa.u[0] = cvtpk(lo4.x, lo4.y);
        fa.u[1] = cvtpk(lo4.z, lo4.w);
        fa.u[2] = cvtpk(hi4.x, hi4.y);
        fa.u[3] = cvtpk(hi4.z, hi4.w);
        af[mf] = fa.v;
      }
      #pragma unroll
      for (int nf = 0; nf < 4; ++nf){
        int r   = wc*64 + nf*16 + lr;
        int idx = (r*64 + kk*32 + lk*8) ^ ((r & 7) << 3);
        bfr[nf] = *(bf16x8*)&lds_b[idx];
      }
      #pragma unroll
      for (int mf = 0; mf < 4; ++mf)
        #pragma unroll
        for (int nf = 0; nf < 4; ++nf)
          acc[mf][nf] = __builtin_amdgcn_mfma_f32_16x16x32_bf16(
              af[mf], bfr[nf], acc[mf][nf], 0, 0, 0);
    }
    __syncthreads();
  }

  // scores epilogue: tanh + dot w2, reduce over 16 col-lanes, atomicAdd
  #pragma unroll
  for (int mf = 0; mf < 4; ++mf){
    float part[4] = {0.f,0.f,0.f,0.f};
    #pragma unroll
    for (int nf = 0; nf < 4; ++nf){
      int gc = colBase + wc*64 + nf*16 + lr;
      float b = bias[gc], wv = w2[gc];
      #pragma unroll
      for (int r = 0; r < 4; ++r)
        part[r] += fast_tanh(acc[mf][nf][r] + b) * wv;
    }
    #pragma unroll
    for (int r = 0; r < 4; ++r){
      part[r] += __shfl_xor(part[r], 1);
      part[r] += __shfl_xor(part[r], 2);
      part[r] += __shfl_xor(part[r], 4);
      part[r] += __shfl_xor(part[r], 8);
    }
    if (lr == 0){
      int gr = rowBase + wr*64 + mf*16 + lk*4;
      #pragma unroll
      for (int r = 0; r < 4; ++r)
        if (gr + r < M) atomicAdd(&out[gr + r], part[r]);
    }
  }
}

// ---------------------------------------------------------------------------
// GEMM2 (pure bf16, m97 structure): out[M,outStride] = A @ Bm^T + bias
// ---------------------------------------------------------------------------
__launch_bounds__(256, 2)
__global__ void gemm2_bf16(const short* __restrict__ A,
                           const short* __restrict__ Bm,
                           const float* __restrict__ bias,
                           float* __restrict__ out,
                           int M, int outStride)
{
  __shared__ short lds_a[128*64];
  __shared__ short lds_b[128*64];

  const int tid  = threadIdx.x;
  const int lane = tid & 63;
  const int w    = tid >> 6;
  const int wr   = w >> 1, wc = w & 1;
  const int lr   = lane & 15;
  const int lk   = lane >> 4;

  const int colBase = blockIdx.x * 128;
  const int rowBase = blockIdx.y * 128;

  f32x4 acc[4][4];
  #pragma unroll
  for (int i = 0; i < 4; ++i)
    #pragma unroll
    for (int j = 0; j < 4; ++j)
      acc[i][j] = (f32x4){0.f, 0.f, 0.f, 0.f};

  const int subrow = lane >> 3;
  const int gpre   = lane & 7;

  for (int kt = 0; kt < 512/64; ++kt){
    const int kOff = kt * 64;
    #pragma unroll
    for (int c = 0; c < 4; ++c){
      int r    = w*32 + c*8 + subrow;
      int gran = gpre ^ (r & 7);
      int gA   = rowBase + r; if (gA > M-1) gA = M-1;
      gload16(A  + (size_t)gA*512 + kOff + gran*8, &lds_a[(w*32 + c*8)*64]);
      int gB   = colBase + r;
      gload16(Bm + (size_t)gB*512 + kOff + gran*8, &lds_b[(w*32 + c*8)*64]);
    }
    __syncthreads();
    #pragma unroll
    for (int kk = 0; kk < 2; ++kk){
      bf16x8 af[4], bfr[4];
      #pragma unroll
      for (int mf = 0; mf < 4; ++mf){
        int r   = wr*64 + mf*16 + lr;
        int idx = (r*64 + kk*32 + lk*8) ^ ((r & 7) << 3);
        af[mf] = *(bf16x8*)&lds_a[idx];
      }
      #pragma unroll
      for (int nf = 0; nf < 4; ++nf){
        int r   = wc*64 + nf*16 + lr;
        int idx = (r*64 + kk*32 + lk*8) ^ ((r & 7) << 3);
        bfr[nf] = *(bf16x8*)&lds_b[idx];
      }
      #pragma unroll
      for (int mf = 0; mf < 4; ++mf)
        #pragma unroll
        for (int nf = 0; nf < 4; ++nf)
          acc[mf][nf] = __builtin_amdgcn_mfma_f32_16x16x32_bf16(
              af[mf], bfr[nf], acc[mf][nf], 0, 0, 0);
    }
    __syncthreads();
  }

  #pragma unroll
  for (int mf = 0; mf < 4; ++mf){
    int gr = rowBase + wr*64 + mf*16 + lk*4;
    #pragma unroll
    for (int nf = 0; nf < 4; ++nf){
      int gc = colBase + wc*64 + nf*16 + lr;
      float b = bias[gc];
      #pragma unroll
      for (int r = 0; r < 4; ++r)
        if (gr + r < M) out[(size_t)(gr + r)*outStride + gc] = acc[mf][nf][r] + b;
    }
  }
}

// ---------------------------------------------------------------------------
__global__ void edge_pass1(const int* __restrict__ edge, int E,
                           const float* __restrict__ scores,
                           unsigned* __restrict__ smax_o,
                           int* __restrict__ hist)
{
  int e = blockIdx.x*256 + threadIdx.x;
  if (e >= E) return;
  int p = edge[e], l = edge[E + e];
  atomicMax(&smax_o[p], f2ord(scores[l]));
  atomicAdd(&hist[p], 1);
}

__global__ void scan_kernel(const int* __restrict__ hist,
                            int* __restrict__ offsets, int P)
{
  __shared__ int s[1024];
  int t = threadIdx.x;
  int local[16]; int sum = 0;
  #pragma unroll
  for (int i = 0; i < 16; ++i){
    int idx = t*16 + i;
    local[i] = (idx < P) ? hist[idx] : 0;
    sum += local[i];
  }
  s[t] = sum;
  __syncthreads();
  for (int off = 1; off < 1024; off <<= 1){
    int v = (t >= off) ? s[t - off] : 0;
    __syncthreads();
    s[t] += v;
    __syncthreads();
  }
  int run = s[t] - sum;             // exclusive prefix
  #pragma unroll
  for (int i = 0; i < 16; ++i){
    int idx = t*16 + i;
    if (idx < P) offsets[idx] = run;
    run += local[i];
  }
}

__global__ void edge_pass2(const int* __restrict__ edge, int E,
                           const float* __restrict__ scores,
                           const unsigned* __restrict__ smax_o,
                           float* __restrict__ ex,
                           float* __restrict__ esum,
                           const int* __restrict__ offsets,
                           int* __restrict__ cursor,
                           int* __restrict__ sorted)
{
  int e = blockIdx.x*256 + threadIdx.x;
  if (e >= E) return;
  int p = edge[e], l = edge[E + e];
  float v = __expf(scores[l] - ord2f(smax_o[p]));
  ex[e] = v;
  atomicAdd(&esum[p], v);
  int pos = atomicAdd(&cursor[p], 1);
  sorted[offsets[p] + pos] = e;
}

// one block per patient: 256 threads x 2 cols, writes packed bf16
__global__ void agg_kernel(const int* __restrict__ edge, int E,
                           const float* __restrict__ lesion_x,
                           const float* __restrict__ ex,
                           const float* __restrict__ esum,
                           const int* __restrict__ offsets,
                           const int* __restrict__ hist,
                           const int* __restrict__ sorted,
                           unsigned* __restrict__ aggb)
{
  int p = blockIdx.x;
  int n = hist[p];
  if (n == 0) return;               // row stays zero (memset)
  int start = offsets[p];
  float inv = 1.f / fmaxf(esum[p], 1e-12f);
  int t = threadIdx.x;
  float a0 = 0.f, a1 = 0.f;
  for (int i = 0; i < n; ++i){
    int e = sorted[start + i];
    int l = edge[E + e];
    float alpha = ex[e] * inv;
    float2 f = *(const float2*)(lesion_x + (size_t)l*512 + t*2);
    a0 += alpha * f.x;
    a1 += alpha * f.y;
  }
  aggb[(size_t)p*256 + t] = cvtpk(a0, a1);
}

// in-place LayerNorm over rows of 768 in d_out
__global__ void ln_kernel(float* __restrict__ out,
                          const float* __restrict__ gamma,
                          const float* __restrict__ beta)
{
  __shared__ float red1[4];
  __shared__ float red2[4];
  int p = blockIdx.x;
  float* row = out + (size_t)p*768;
  int t = threadIdx.x;
  float v0 = row[t], v1 = row[t+256], v2 = row[t+512];
  float s = v0 + v1 + v2;
  #pragma unroll
  for (int off = 32; off; off >>= 1) s += __shfl_down(s, off);
  int lane = t & 63, wv = t >> 6;
  if (lane == 0) red1[wv] = s;
  __syncthreads();
  float mean = (red1[0]+red1[1]+red1[2]+red1[3]) * (1.f/768.f);
  float d0 = v0-mean, d1 = v1-mean, d2 = v2-mean;
  float q = d0*d0 + d1*d1 + d2*d2;
  #pragma unroll
  for (int off = 32; off; off >>= 1) q += __shfl_down(q, off);
  if (lane == 0) red2[wv] = q;
  __syncthreads();
  float var = (red2[0]+red2[1]+red2[2]+red2[3]) * (1.f/768.f);
  float inv = rsqrtf(var + 1e-5f);
  row[t]     = d0*inv*gamma[t]     + beta[t];
  row[t+256] = d1*inv*gamma[t+256] + beta[t+256];
  row[t+512] = d2*inv*gamma[t+512] + beta[t+512];
}

// ---------------------------------------------------------------------------
extern "C" void kernel_launch(void* const* d_in, const int* in_sizes, int n_in,
                              void* d_out, int out_size, void* d_ws, size_t ws_size,
                              hipStream_t stream)
{
  const float* lesion_x = (const float*)d_in[0];
  const int*   edge     = (const int*)d_in[1];
  const float* W1    = (const float*)d_in[3];
  const float* b1    = (const float*)d_in[4];
  const float* W2    = (const float*)d_in[5];
  // d_in[6] = b2 — uniform shift, cancels in softmax
  const float* Wp    = (const float*)d_in[7];
  const float* bp    = (const float*)d_in[8];
  const float* gamma = (const float*)d_in[9];
  const float* beta  = (const float*)d_in[10];

  const int L = in_sizes[0] / D_DIM;
  const int E = in_sizes[1] / 2;
  const int P = out_size / O_DIM;

  auto al = [](size_t x){ return (x + 255) & ~(size_t)255; };
  char* ws = (char*)d_ws;
  size_t oScores = 0;
  size_t oSmax   = oScores + al((size_t)L*4);
  size_t oEsum   = oSmax   + al((size_t)P*4);
  size_t oHist   = oEsum   + al((size_t)P*4);
  size_t oCursor = oHist   + al((size_t)P*4);
  size_t smallEnd= oCursor + al((size_t)P*4);
  size_t oAggB   = smallEnd;                        // P*512*2 bf16
  size_t aggEnd  = oAggB   + al((size_t)P*D_DIM*2);
  size_t oOff    = aggEnd;
  size_t oEx     = oOff    + al((size_t)P*4);
  size_t oSorted = oEx     + al((size_t)E*4);
  size_t oW1b    = oSorted + al((size_t)E*4);
  size_t oWpb    = oW1b    + al((size_t)H_DIM*D_DIM*2);
  size_t need    = oWpb    + al((size_t)O_DIM*D_DIM*2);
  (void)need; // ws_size is ~1.6 GB per harness poison fill; need ~25 MB

  float*    scores = (float*)(ws + oScores);
  unsigned* smax_o = (unsigned*)(ws + oSmax);
  float*    esum   = (float*)(ws + oEsum);
  int*      hist   = (int*)(ws + oHist);
  int*      cursor = (int*)(ws + oCursor);
  unsigned* aggb   = (unsigned*)(ws + oAggB);
  int*      offs   = (int*)(ws + oOff);
  float*    ex     = (float*)(ws + oEx);
  int*      sorted = (int*)(ws + oSorted);
  short*    W1b    = (short*)(ws + oW1b);
  short*    Wpb    = (short*)(ws + oWpb);

  hipMemsetAsync(d_ws, 0, smallEnd, stream);
  hipMemsetAsync(ws + oAggB, 0, (size_t)P*D_DIM*2, stream);

  dim3 b256(256);
  int eb = (E + 255) / 256;

  // weight conversions (tiny, BW-bound)
  cvt_bf16<<<128, b256, 0, stream>>>(W1, (unsigned short*)W1b, H_DIM*D_DIM/8);
  cvt_bf16<<<192, b256, 0, stream>>>(Wp, (unsigned short*)Wpb, O_DIM*D_DIM/8);

  // GEMM1: fp32 A direct, flat grid + XCD swizzle
  int nRow = (L + 127) / 128;
  int nwg  = 4 * nRow;
  gemm1_f32a<<<nwg, b256, 0, stream>>>(lesion_x, W1b, b1, W2, scores, L, nwg);

  edge_pass1<<<eb, b256, 0, stream>>>(edge, E, scores, smax_o, hist);
  scan_kernel<<<1, 1024, 0, stream>>>(hist, offs, P);
  edge_pass2<<<eb, b256, 0, stream>>>(edge, E, scores, smax_o, ex, esum,
                                      offs, cursor, sorted);
  agg_kernel<<<P, b256, 0, stream>>>(edge, E, lesion_x, ex, esum, offs,
                                     hist, sorted, aggb);
  gemm2_bf16<<<dim3(O_DIM/128, P/128), b256, 0, stream>>>(
      (const short*)aggb, Wpb, bp, (float*)d_out, P, O_DIM);
  ln_kernel<<<P, b256, 0, stream>>>((float*)d_out, gamma, beta);
}

// Round 4
// 413.661 us; speedup vs baseline: 1.7222x; 1.0396x over previous
//
#include <hip/hip_runtime.h>
#include <hip/hip_bf16.h>

#define D_DIM 512
#define H_DIM 512
#define O_DIM 768

using bf16x8 = __attribute__((ext_vector_type(8))) short;
using f32x4  = __attribute__((ext_vector_type(4))) float;

static __device__ __forceinline__ unsigned short f2bf(float f){
  unsigned u = __float_as_uint(f);
  u += 0x7fffu + ((u >> 16) & 1u);   // RNE
  return (unsigned short)(u >> 16);
}

// packed fp32x2 -> bf16x2 (RNE), one VALU inst
static __device__ __forceinline__ unsigned cvtpk(float lo, float hi){
  unsigned r;
  asm("v_cvt_pk_bf16_f32 %0, %1, %2" : "=v"(r) : "v"(lo), "v"(hi));
  return r;
}

static __device__ __forceinline__ float bflo(unsigned u){
  return __uint_as_float(u << 16);
}
static __device__ __forceinline__ float bfhi(unsigned u){
  return __uint_as_float(u & 0xffff0000u);
}

static __device__ __forceinline__ float fast_tanh(float x){
  float e = __expf(2.f * x);         // inf-safe
  return 1.f - 2.f / (e + 1.f);
}

// ordered-uint encoding so atomicMax(unsigned) == float max
static __device__ __forceinline__ unsigned f2ord(float f){
  unsigned u = __float_as_uint(f);
  return (u & 0x80000000u) ? ~u : (u | 0x80000000u);
}
static __device__ __forceinline__ float ord2f(unsigned u){
  u = (u & 0x80000000u) ? (u & 0x7fffffffu) : ~u;
  return __uint_as_float(u);
}

// async global->LDS, 16B per lane, wave-uniform LDS base + lane*16 dest
static __device__ __forceinline__ void gload16(const void* g, void* l){
  __builtin_amdgcn_global_load_lds(
      (const __attribute__((address_space(1))) void*)g,
      (__attribute__((address_space(3))) void*)l, 16, 0, 0);
}

// ---------------------------------------------------------------------------
// fp32 -> bf16 pack (weights only; tiny)
// ---------------------------------------------------------------------------
__global__ void cvt_bf16(const float* __restrict__ in,
                         unsigned short* __restrict__ out, int n8)
{
  int stride = gridDim.x * blockDim.x;
  for (int i = blockIdx.x*blockDim.x + threadIdx.x; i < n8; i += stride){
    const float4* p = (const float4*)in + (size_t)i*2;
    float4 a = p[0], b = p[1];
    uint4 pk = { cvtpk(a.x,a.y) | 0u, 0u, 0u, 0u };
    pk.x = cvtpk(a.x, a.y);
    pk.y = cvtpk(a.z, a.w);
    pk.z = cvtpk(b.x, b.y);
    pk.w = cvtpk(b.z, b.w);
    ((uint4*)out)[i] = pk;
  }
}

// ---------------------------------------------------------------------------
// GEMM1: scores = sum_cols tanh(A_fp32 @ W1b^T + b1) * w2   (atomicAdd partials)
// A reg-staged: coalesced float4 loads -> cvt_pk -> ds_write_b64 into the
// 0-conflict bf16 XOR-swizzled layout. B staged bf16 via global_load_lds.
// colBase==0 blocks additionally store the packed bf16 A tile to Ab (so the
// downstream gather reads half the bytes). 128x128 tile, BK=64, 4 waves.
// Flat grid + bijective XCD chunked swizzle (N-fast).
// ---------------------------------------------------------------------------
__launch_bounds__(256, 3)
__global__ void gemm1_rs(const float* __restrict__ A,
                         const short* __restrict__ Bm,
                         const float* __restrict__ bias,
                         const float* __restrict__ w2,
                         float* __restrict__ out,
                         short* __restrict__ Ab,
                         int M, int nwg)
{
  __shared__ short lds_a[128*64];
  __shared__ short lds_b[128*64];

  // bijective XCD-chunked swizzle (m204), then N-fast decode
  const int q  = nwg >> 3, rr = nwg & 7;
  const int xcd = blockIdx.x & 7, bidx = blockIdx.x >> 3;
  const int swz = (xcd < rr ? xcd*(q+1) : rr*(q+1) + (xcd-rr)*q) + bidx;
  const int colBase = (swz & 3) * 128;
  const int rowBase = (swz >> 2) * 128;
  const bool writeAb = (colBase == 0);

  const int tid  = threadIdx.x;
  const int lane = tid & 63;
  const int w    = tid >> 6;
  const int wr   = w >> 1, wc = w & 1;
  const int lr   = lane & 15;
  const int lk   = lane >> 4;

  // A staging decomposition: 16 rows/instruction, 16 float4-granules/row
  const int srow = tid >> 4;        // 0..15
  const int sgf  = tid & 15;        // float4 granule in 256B fp32 row
  // B staging (gload16): 4 calls x 8 rows per wave
  const int rlocB = lane >> 3;
  const int jB    = lane & 7;

  f32x4 acc[4][4];
  #pragma unroll
  for (int i = 0; i < 4; ++i)
    #pragma unroll
    for (int j = 0; j < 4; ++j)
      acc[i][j] = (f32x4){0.f, 0.f, 0.f, 0.f};

  for (int kt = 0; kt < 512/64; ++kt){
    const int kOff = kt * 64;
    // B async direct-to-LDS
    #pragma unroll
    for (int c = 0; c < 4; ++c){
      int rt = w*32 + c*8 + rlocB;
      int js = jB ^ (rt & 7);
      gload16(Bm + (size_t)(colBase + rt)*512 + kOff + js*8,
              &lds_b[(w*32 + c*8)*64]);
    }
    // A: coalesced fp32 loads (issue all 8 first for ILP)
    float4 va[8];
    #pragma unroll
    for (int c = 0; c < 8; ++c){
      int gA = rowBase + c*16 + srow; if (gA > M-1) gA = M-1;
      va[c] = *(const float4*)(A + (size_t)gA*512 + kOff + sgf*4);
    }
    #pragma unroll
    for (int c = 0; c < 8; ++c){
      int rt = c*16 + srow;
      uint2 pk = { cvtpk(va[c].x, va[c].y), cvtpk(va[c].z, va[c].w) };
      int sidx = (rt*64 + sgf*4) ^ ((rt & 7) << 3);   // shorts, 16B-granule XOR
      *(uint2*)&lds_a[sidx] = pk;
      if (writeAb){
        int gA = rowBase + rt;
        if (gA < M) *(uint2*)(Ab + (size_t)gA*512 + kOff + sgf*4) = pk;
      }
    }
    __syncthreads();
    #pragma unroll
    for (int kk = 0; kk < 2; ++kk){
      bf16x8 af[4], bfr[4];
      #pragma unroll
      for (int mf = 0; mf < 4; ++mf){
        int r   = wr*64 + mf*16 + lr;
        int idx = (r*64 + kk*32 + lk*8) ^ ((r & 7) << 3);
        af[mf] = *(bf16x8*)&lds_a[idx];
      }
      #pragma unroll
      for (int nf = 0; nf < 4; ++nf){
        int r   = wc*64 + nf*16 + lr;
        int idx = (r*64 + kk*32 + lk*8) ^ ((r & 7) << 3);
        bfr[nf] = *(bf16x8*)&lds_b[idx];
      }
      #pragma unroll
      for (int mf = 0; mf < 4; ++mf)
        #pragma unroll
        for (int nf = 0; nf < 4; ++nf)
          acc[mf][nf] = __builtin_amdgcn_mfma_f32_16x16x32_bf16(
              af[mf], bfr[nf], acc[mf][nf], 0, 0, 0);
    }
    __syncthreads();
  }

  // scores epilogue: tanh + dot w2, reduce over 16 col-lanes, atomicAdd
  #pragma unroll
  for (int mf = 0; mf < 4; ++mf){
    float part[4] = {0.f,0.f,0.f,0.f};
    #pragma unroll
    for (int nf = 0; nf < 4; ++nf){
      int gc = colBase + wc*64 + nf*16 + lr;
      float b = bias[gc], wv = w2[gc];
      #pragma unroll
      for (int r = 0; r < 4; ++r)
        part[r] += fast_tanh(acc[mf][nf][r] + b) * wv;
    }
    #pragma unroll
    for (int r = 0; r < 4; ++r){
      part[r] += __shfl_xor(part[r], 1);
      part[r] += __shfl_xor(part[r], 2);
      part[r] += __shfl_xor(part[r], 4);
      part[r] += __shfl_xor(part[r], 8);
    }
    if (lr == 0){
      int gr = rowBase + wr*64 + mf*16 + lk*4;
      #pragma unroll
      for (int r = 0; r < 4; ++r)
        if (gr + r < M) atomicAdd(&out[gr + r], part[r]);
    }
  }
}

// ---------------------------------------------------------------------------
// GEMM2 (pure bf16, m97 structure): out[M,outStride] = A @ Bm^T + bias
// ---------------------------------------------------------------------------
__launch_bounds__(256, 2)
__global__ void gemm2_bf16(const short* __restrict__ A,
                           const short* __restrict__ Bm,
                           const float* __restrict__ bias,
                           float* __restrict__ out,
                           int M, int outStride)
{
  __shared__ short lds_a[128*64];
  __shared__ short lds_b[128*64];

  const int tid  = threadIdx.x;
  const int lane = tid & 63;
  const int w    = tid >> 6;
  const int wr   = w >> 1, wc = w & 1;
  const int lr   = lane & 15;
  const int lk   = lane >> 4;

  const int colBase = blockIdx.x * 128;
  const int rowBase = blockIdx.y * 128;

  f32x4 acc[4][4];
  #pragma unroll
  for (int i = 0; i < 4; ++i)
    #pragma unroll
    for (int j = 0; j < 4; ++j)
      acc[i][j] = (f32x4){0.f, 0.f, 0.f, 0.f};

  const int subrow = lane >> 3;
  const int gpre   = lane & 7;

  for (int kt = 0; kt < 512/64; ++kt){
    const int kOff = kt * 64;
    #pragma unroll
    for (int c = 0; c < 4; ++c){
      int r    = w*32 + c*8 + subrow;
      int gran = gpre ^ (r & 7);
      int gA   = rowBase + r; if (gA > M-1) gA = M-1;
      gload16(A  + (size_t)gA*512 + kOff + gran*8, &lds_a[(w*32 + c*8)*64]);
      int gB   = colBase + r;
      gload16(Bm + (size_t)gB*512 + kOff + gran*8, &lds_b[(w*32 + c*8)*64]);
    }
    __syncthreads();
    #pragma unroll
    for (int kk = 0; kk < 2; ++kk){
      bf16x8 af[4], bfr[4];
      #pragma unroll
      for (int mf = 0; mf < 4; ++mf){
        int r   = wr*64 + mf*16 + lr;
        int idx = (r*64 + kk*32 + lk*8) ^ ((r & 7) << 3);
        af[mf] = *(bf16x8*)&lds_a[idx];
      }
      #pragma unroll
      for (int nf = 0; nf < 4; ++nf){
        int r   = wc*64 + nf*16 + lr;
        int idx = (r*64 + kk*32 + lk*8) ^ ((r & 7) << 3);
        bfr[nf] = *(bf16x8*)&lds_b[idx];
      }
      #pragma unroll
      for (int mf = 0; mf < 4; ++mf)
        #pragma unroll
        for (int nf = 0; nf < 4; ++nf)
          acc[mf][nf] = __builtin_amdgcn_mfma_f32_16x16x32_bf16(
              af[mf], bfr[nf], acc[mf][nf], 0, 0, 0);
    }
    __syncthreads();
  }

  #pragma unroll
  for (int mf = 0; mf < 4; ++mf){
    int gr = rowBase + wr*64 + mf*16 + lk*4;
    #pragma unroll
    for (int nf = 0; nf < 4; ++nf){
      int gc = colBase + wc*64 + nf*16 + lr;
      float b = bias[gc];
      #pragma unroll
      for (int r = 0; r < 4; ++r)
        if (gr + r < M) out[(size_t)(gr + r)*outStride + gc] = acc[mf][nf][r] + b;
    }
  }
}

// ---------------------------------------------------------------------------
__global__ void edge_pass1(const int* __restrict__ edge, int E,
                           const float* __restrict__ scores,
                           unsigned* __restrict__ smax_o,
                           int* __restrict__ hist)
{
  int e = blockIdx.x*256 + threadIdx.x;
  if (e >= E) return;
  int p = edge[e], l = edge[E + e];
  atomicMax(&smax_o[p], f2ord(scores[l]));
  atomicAdd(&hist[p], 1);
}

__global__ void scan_kernel(const int* __restrict__ hist,
                            int* __restrict__ offsets, int P)
{
  __shared__ int s[1024];
  int t = threadIdx.x;
  int local[16]; int sum = 0;
  #pragma unroll
  for (int i = 0; i < 16; ++i){
    int idx = t*16 + i;
    local[i] = (idx < P) ? hist[idx] : 0;
    sum += local[i];
  }
  s[t] = sum;
  __syncthreads();
  for (int off = 1; off < 1024; off <<= 1){
    int v = (t >= off) ? s[t - off] : 0;
    __syncthreads();
    s[t] += v;
    __syncthreads();
  }
  int run = s[t] - sum;             // exclusive prefix
  #pragma unroll
  for (int i = 0; i < 16; ++i){
    int idx = t*16 + i;
    if (idx < P) offsets[idx] = run;
    run += local[i];
  }
}

__global__ void edge_pass2(const int* __restrict__ edge, int E,
                           const float* __restrict__ scores,
                           const unsigned* __restrict__ smax_o,
                           float* __restrict__ ex,
                           float* __restrict__ esum,
                           const int* __restrict__ offsets,
                           int* __restrict__ cursor,
                           int* __restrict__ sorted)
{
  int e = blockIdx.x*256 + threadIdx.x;
  if (e >= E) return;
  int p = edge[e], l = edge[E + e];
  float v = __expf(scores[l] - ord2f(smax_o[p]));
  ex[e] = v;
  atomicAdd(&esum[p], v);
  int pos = atomicAdd(&cursor[p], 1);
  sorted[offsets[p] + pos] = e;
}

// one WAVE per patient (4 patients/block): gathers bf16 rows (1KB/edge)
__global__ void agg_kernel(const int* __restrict__ edge, int E,
                           const short* __restrict__ Ab,
                           const float* __restrict__ ex,
                           const float* __restrict__ esum,
                           const int* __restrict__ offsets,
                           const int* __restrict__ hist,
                           const int* __restrict__ sorted,
                           unsigned* __restrict__ aggb)
{
  int p    = blockIdx.x*4 + (threadIdx.x >> 6);
  int lane = threadIdx.x & 63;
  int n = hist[p];
  if (n == 0) return;               // row stays zero (memset)
  int start = offsets[p];
  float inv = 1.f / fmaxf(esum[p], 1e-12f);
  float a[8] = {0.f,0.f,0.f,0.f,0.f,0.f,0.f,0.f};
  for (int i = 0; i < n; ++i){
    int e = sorted[start + i];
    int l = edge[E + e];
    float alpha = ex[e] * inv;
    uint4 u = *(const uint4*)(Ab + (size_t)l*512 + lane*8);
    a[0] += alpha * bflo(u.x);  a[1] += alpha * bfhi(u.x);
    a[2] += alpha * bflo(u.y);  a[3] += alpha * bfhi(u.y);
    a[4] += alpha * bflo(u.z);  a[5] += alpha * bfhi(u.z);
    a[6] += alpha * bflo(u.w);  a[7] += alpha * bfhi(u.w);
  }
  uint4 o = { cvtpk(a[0],a[1]), cvtpk(a[2],a[3]),
              cvtpk(a[4],a[5]), cvtpk(a[6],a[7]) };
  *(uint4*)&aggb[(size_t)p*256 + lane*4] = o;
}

// in-place LayerNorm over rows of 768 in d_out
__global__ void ln_kernel(float* __restrict__ out,
                          const float* __restrict__ gamma,
                          const float* __restrict__ beta)
{
  __shared__ float red1[4];
  __shared__ float red2[4];
  int p = blockIdx.x;
  float* row = out + (size_t)p*768;
  int t = threadIdx.x;
  float v0 = row[t], v1 = row[t+256], v2 = row[t+512];
  float s = v0 + v1 + v2;
  #pragma unroll
  for (int off = 32; off; off >>= 1) s += __shfl_down(s, off);
  int lane = t & 63, wv = t >> 6;
  if (lane == 0) red1[wv] = s;
  __syncthreads();
  float mean = (red1[0]+red1[1]+red1[2]+red1[3]) * (1.f/768.f);
  float d0 = v0-mean, d1 = v1-mean, d2 = v2-mean;
  float qq = d0*d0 + d1*d1 + d2*d2;
  #pragma unroll
  for (int off = 32; off; off >>= 1) qq += __shfl_down(qq, off);
  if (lane == 0) red2[wv] = qq;
  __syncthreads();
  float var = (red2[0]+red2[1]+red2[2]+red2[3]) * (1.f/768.f);
  float inv = rsqrtf(var + 1e-5f);
  row[t]     = d0*inv*gamma[t]     + beta[t];
  row[t+256] = d1*inv*gamma[t+256] + beta[t+256];
  row[t+512] = d2*inv*gamma[t+512] + beta[t+512];
}

// ---------------------------------------------------------------------------
extern "C" void kernel_launch(void* const* d_in, const int* in_sizes, int n_in,
                              void* d_out, int out_size, void* d_ws, size_t ws_size,
                              hipStream_t stream)
{
  const float* lesion_x = (const float*)d_in[0];
  const int*   edge     = (const int*)d_in[1];
  const float* W1    = (const float*)d_in[3];
  const float* b1    = (const float*)d_in[4];
  const float* W2    = (const float*)d_in[5];
  // d_in[6] = b2 — uniform shift, cancels in softmax
  const float* Wp    = (const float*)d_in[7];
  const float* bp    = (const float*)d_in[8];
  const float* gamma = (const float*)d_in[9];
  const float* beta  = (const float*)d_in[10];

  const int L = in_sizes[0] / D_DIM;
  const int E = in_sizes[1] / 2;
  const int P = out_size / O_DIM;

  auto al = [](size_t x){ return (x + 255) & ~(size_t)255; };
  char* ws = (char*)d_ws;
  size_t oScores = 0;
  size_t oSmax   = oScores + al((size_t)L*4);
  size_t oEsum   = oSmax   + al((size_t)P*4);
  size_t oHist   = oEsum   + al((size_t)P*4);
  size_t oCursor = oHist   + al((size_t)P*4);
  size_t smallEnd= oCursor + al((size_t)P*4);
  size_t oAggB   = smallEnd;                        // P*512*2 bf16
  size_t aggEnd  = oAggB   + al((size_t)P*D_DIM*2);
  size_t oOff    = aggEnd;
  size_t oEx     = oOff    + al((size_t)P*4);
  size_t oSorted = oEx     + al((size_t)E*4);
  size_t oW1b    = oSorted + al((size_t)E*4);
  size_t oWpb    = oW1b    + al((size_t)H_DIM*D_DIM*2);
  size_t oAb     = oWpb    + al((size_t)O_DIM*D_DIM*2);
  size_t need    = oAb     + al((size_t)L*D_DIM*2);
  (void)need; // ~230 MB; harness ws is ~1.6 GB

  float*    scores = (float*)(ws + oScores);
  unsigned* smax_o = (unsigned*)(ws + oSmax);
  float*    esum   = (float*)(ws + oEsum);
  int*      hist   = (int*)(ws + oHist);
  int*      cursor = (int*)(ws + oCursor);
  unsigned* aggb   = (unsigned*)(ws + oAggB);
  int*      offs   = (int*)(ws + oOff);
  float*    ex     = (float*)(ws + oEx);
  int*      sorted = (int*)(ws + oSorted);
  short*    W1b    = (short*)(ws + oW1b);
  short*    Wpb    = (short*)(ws + oWpb);
  short*    Ab     = (short*)(ws + oAb);

  hipMemsetAsync(d_ws, 0, smallEnd, stream);
  hipMemsetAsync(ws + oAggB, 0, (size_t)P*D_DIM*2, stream);

  dim3 b256(256);
  int eb = (E + 255) / 256;

  // weight conversions (tiny, BW-bound)
  cvt_bf16<<<128, b256, 0, stream>>>(W1, (unsigned short*)W1b, H_DIM*D_DIM/8);
  cvt_bf16<<<192, b256, 0, stream>>>(Wp, (unsigned short*)Wpb, O_DIM*D_DIM/8);

  // GEMM1: fp32 A reg-staged -> bf16 LDS; emits bf16 A copy to Ab
  int nRow = (L + 127) / 128;
  int nwg  = 4 * nRow;
  gemm1_rs<<<nwg, b256, 0, stream>>>(lesion_x, W1b, b1, W2, scores, Ab, L, nwg);

  edge_pass1<<<eb, b256, 0, stream>>>(edge, E, scores, smax_o, hist);
  scan_kernel<<<1, 1024, 0, stream>>>(hist, offs, P);
  edge_pass2<<<eb, b256, 0, stream>>>(edge, E, scores, smax_o, ex, esum,
                                      offs, cursor, sorted);
  agg_kernel<<<P/4, b256, 0, stream>>>(edge, E, Ab, ex, esum, offs,
                                       hist, sorted, aggb);
  gemm2_bf16<<<dim3(O_DIM/128, P/128), b256, 0, stream>>>(
      (const short*)aggb, Wpb, bp, (float*)d_out, P, O_DIM);
  ln_kernel<<<P, b256, 0, stream>>>((float*)d_out, gamma, beta);
}